// Round 4
// baseline (2401.640 us; speedup 1.0000x reference)
//
#include <hip/hip_runtime.h>
#include <hip/hip_fp16.h>
#include <hip/hip_cooperative_groups.h>

namespace cg = cooperative_groups;

#define H_  1024
#define W_  1024
#define HW_ (H_*W_)
#define M_  524288
#define SC_ 0.03125f

#define SWZ(a) ((a) + ((a)>>4))
// chunked XCD swizzle: XCD x owns rows [x*128, x*128+128)
#define ROWSWZ(b) ((((b)&7)<<7) | ((b)>>3))

// ---------------------------------------------------------------- complex mul
__device__ __forceinline__ float2 cmulf(float2 a, float2 b){
  return make_float2(fmaf(a.x,b.x,-(a.y*b.y)), fmaf(a.x,b.y,a.y*b.x));
}

// ---------------------------------------------------------------- radix-4 bfly
template<int DIR>
__device__ __forceinline__ void bfly4(float2 v[4], int j, int Ns){
  if (Ns>1){
    float ang = ((DIR>0)?6.28318530717958647692f:-6.28318530717958647692f)
                * (float)(j&(Ns-1)) / (float)(4*Ns);
    float s,c; __sincosf(ang,&s,&c);
    float2 w1=make_float2(c,s);
    float2 w2=cmulf(w1,w1);
    float2 w3=cmulf(w2,w1);
    v[1]=cmulf(v[1],w1); v[2]=cmulf(v[2],w2); v[3]=cmulf(v[3],w3);
  }
  float2 t0=make_float2(v[0].x+v[2].x, v[0].y+v[2].y);
  float2 t2=make_float2(v[0].x-v[2].x, v[0].y-v[2].y);
  float2 t1=make_float2(v[1].x+v[3].x, v[1].y+v[3].y);
  float2 t3=make_float2(v[1].x-v[3].x, v[1].y-v[3].y);
  float2 t3r=(DIR<0)?make_float2(t3.y,-t3.x):make_float2(-t3.y,t3.x);
  v[0]=make_float2(t0.x+t1.x,  t0.y+t1.y);
  v[1]=make_float2(t2.x+t3r.x, t2.y+t3r.y);
  v[2]=make_float2(t0.x-t1.x,  t0.y-t1.y);
  v[3]=make_float2(t2.x-t3r.x, t2.y-t3r.y);
}

template<int DIR, int NS>
__device__ __forceinline__ void fft_stage(int j, const float2* src, float2* dst){
  float2 v[4];
#pragma unroll
  for(int r=0;r<4;r++) v[r]=src[SWZ(j+256*r)];
  bfly4<DIR>(v,j,NS);
  int base = ((j & ~(NS-1))<<2) | (j&(NS-1));
#pragma unroll
  for(int r=0;r<4;r++) dst[SWZ(base+NS*r)]=v[r];
}

template<int DIR>
__device__ __forceinline__ void fft1024_core(float2 v[4], int j, float2* A, float2* B, float scale){
  bfly4<DIR>(v,j,1);
#pragma unroll
  for(int r=0;r<4;r++) A[SWZ(4*j+r)]=v[r];
  __syncthreads();
  fft_stage<DIR,4 >(j,A,B); __syncthreads();
  fft_stage<DIR,16>(j,B,A); __syncthreads();
  fft_stage<DIR,64>(j,A,B); __syncthreads();
#pragma unroll
  for(int r=0;r<4;r++) v[r]=B[SWZ(j+256*r)];
  bfly4<DIR>(v,j,256);
#pragma unroll
  for(int r=0;r<4;r++){ v[r].x*=scale; v[r].y*=scale; }
}

// ---------------------------------------------------------------- FFT phase device fns
template<int DIR>
__device__ __forceinline__ void dev_fft_row(int row, int tid, const float2* src, float2* dst,
                                            float scale, float2* A, float2* B){
  const float2* s = src + (size_t)row*W_;
  float2 v[4];
#pragma unroll
  for(int r=0;r<4;r++) v[r]=s[tid+256*r];
  fft1024_core<DIR>(v,tid,A,B,scale);
  float2* d = dst + (size_t)row*W_;
#pragma unroll
  for(int r=0;r<4;r++) d[tid+256*r]=v[r];
}

template<int DIR>
__device__ __forceinline__ void dev_fft_col(int unit, int tid, float2* data,
                                            float scale, float2* A, float2* B){
  int col = ROWSWZ(unit);
  float2 v[4];
#pragma unroll
  for(int r=0;r<4;r++) v[r]=data[(size_t)(tid+256*r)*W_ + col];
  fft1024_core<DIR>(v,tid,A,B,scale);
#pragma unroll
  for(int r=0;r<4;r++) data[(size_t)(tid+256*r)*W_ + col]=v[r];
}

template<int DIR>
__global__ __launch_bounds__(256) void k_fft_rows(const float2* src, float2* dst, float scale){
  __shared__ float2 A[1088], B[1088];
  dev_fft_row<DIR>(blockIdx.x, threadIdx.x, src, dst, scale, A, B);
}

template<int DIR>
__global__ __launch_bounds__(256) void k_fft_cols1(float2* data, float scale){
  __shared__ float2 A[1088], B[1088];
  dev_fft_col<DIR>(blockIdx.x, threadIdx.x, data, scale, A, B);
}

// ---------------------------------------------------------------- adjoint accumulation (Gy walk)
__device__ __forceinline__ void adj_cells4(const float4* __restrict__ pd,
                                           const int* __restrict__ off,
                                           int r, int c0,
                                           float axr[4], float ayr[4]){
#pragma unroll
  for(int q=0;q<4;q++){ axr[q]=0.f; ayr[q]=0.f; }
#pragma unroll
  for(int dr=0;dr<2;dr++){
    int br=(r-dr)&1023;
    int rowbase=br<<10;
    if (c0>0){
      int O[6];
#pragma unroll
      for(int q=0;q<6;q++) O[q]=off[rowbase+c0-2+q];
#pragma unroll
      for(int i=0;i<5;i++){
        for(int j=O[i]; j<O[i+1]; j++){
          float4 p=pd[j];
          float wx = dr ? p.x : 1.f-p.x;
          float w0 = wx*(1.f-p.y), w1 = wx*p.y;
          if (i>=1){ axr[i-1]=fmaf(w0,p.z,axr[i-1]); ayr[i-1]=fmaf(w0,p.w,ayr[i-1]); }
          if (i<=3){ axr[i]  =fmaf(w1,p.z,axr[i]);   ayr[i]  =fmaf(w1,p.w,ayr[i]); }
        }
      }
    } else {
      int bw = rowbase+1023;
      int sw = off[bw-1], ew=off[bw];
      for(int j=sw;j<ew;j++){
        float4 p=pd[j];
        float wx = dr ? p.x : 1.f-p.x;
        float w1 = wx*p.y;
        axr[0]=fmaf(w1,p.z,axr[0]); ayr[0]=fmaf(w1,p.w,ayr[0]);
      }
      int O[5];
      O[0] = (rowbase==0)? 0 : off[rowbase-1];
#pragma unroll
      for(int q=1;q<5;q++) O[q]=off[rowbase+q-1];
#pragma unroll
      for(int i=0;i<4;i++){
        for(int j=O[i]; j<O[i+1]; j++){
          float4 p=pd[j];
          float wx = dr ? p.x : 1.f-p.x;
          float w0 = wx*(1.f-p.y), w1 = wx*p.y;
          axr[i]=fmaf(w0,p.z,axr[i]); ayr[i]=fmaf(w0,p.w,ayr[i]);
          if (i<=2){ axr[i+1]=fmaf(w1,p.z,axr[i+1]); ayr[i+1]=fmaf(w1,p.w,ayr[i+1]); }
        }
      }
    }
  }
}

// ---------------------------------------------------------------- init
__global__ __launch_bounds__(256) void k_pack(const float* xr, const float* xi, float2* X, float* t){
  int i = blockIdx.x*256+threadIdx.x;
  if (i<HW_) X[i]=make_float2(xr[i],xi[i]);
  if (blockIdx.x==0 && threadIdx.x<32) t[threadIdx.x]=0.f;
}

__global__ __launch_bounds__(256) void k_hist(const float* kt, int* counts, float* pmax){
  int m = blockIdx.x*256+threadIdx.x;
  float r = 0.f;
  {
    float kx=kt[2*m], ky=kt[2*m+1];
    float dx=kx-0.5f, dy=ky-0.5f;
    r = sqrtf(dx*dx+dy*dy);
    int ix = ((int)floorf(kx*1024.f))&1023;
    int iy = ((int)floorf(ky*1024.f))&1023;
    atomicAdd(&counts[(ix<<10)|iy],1);
  }
  for(int o=32;o>0;o>>=1) r = fmaxf(r, __shfl_down(r,o,64));
  __shared__ float sm[4];
  if((threadIdx.x&63)==0) sm[threadIdx.x>>6]=r;
  __syncthreads();
  if(threadIdx.x==0)
    pmax[blockIdx.x] = fmaxf(fmaxf(sm[0],sm[1]),fmaxf(sm[2],sm[3]));
}

__global__ __launch_bounds__(256) void k_reduce_max(const float* pmax, float* t){
  int tid=threadIdx.x;
  float s=-1e30f;
  for(int k=tid;k<2048;k+=256) s=fmaxf(s,pmax[k]);
  __shared__ float sm[4];
  for(int o=32;o>0;o>>=1) s=fmaxf(s,__shfl_down(s,o,64));
  if((tid&63)==0) sm[tid>>6]=s;
  __syncthreads();
  if(tid==0) t[15]=fmaxf(fmaxf(sm[0],sm[1]),fmaxf(sm[2],sm[3]));
}

// ---------------------------------------------------------------- scan
__global__ __launch_bounds__(256) void k_scan1(const int* cnt, int* off, int* bsum){
  __shared__ int sm[256];
  int base = blockIdx.x*1024;
  int tid = threadIdx.x;
  int4 c = *(const int4*)(cnt + base + tid*4);
  int s = c.x+c.y+c.z+c.w;
  sm[tid]=s; __syncthreads();
  int v=s;
  for(int o=1;o<256;o<<=1){
    int u = (tid>=o)? sm[tid-o]:0;
    __syncthreads();
    v += u; sm[tid]=v;
    __syncthreads();
  }
  int excl = v - s;
  int4 o4;
  o4.x=excl; o4.y=excl+c.x; o4.z=excl+c.x+c.y; o4.w=excl+c.x+c.y+c.z;
  *(int4*)(off+base+tid*4)=o4;
  if (tid==255) bsum[blockIdx.x]=v;
}

__global__ __launch_bounds__(256) void k_scan2(int* bsum){
  __shared__ int sm[256];
  int tid=threadIdx.x;
  int4 c = *(const int4*)(bsum + tid*4);
  int s = c.x+c.y+c.z+c.w;
  sm[tid]=s; __syncthreads();
  int v=s;
  for(int o=1;o<256;o<<=1){
    int u = (tid>=o)? sm[tid-o]:0;
    __syncthreads();
    v += u; sm[tid]=v;
    __syncthreads();
  }
  int excl=v-s;
  int4 o4;
  o4.x=excl; o4.y=excl+c.x; o4.z=excl+c.x+c.y; o4.w=excl+c.x+c.y+c.z;
  *(int4*)(bsum+tid*4)=o4;
}

__global__ __launch_bounds__(256) void k_scan3(int* off, const int* bbase){
  int gid = blockIdx.x*256+threadIdx.x;
  int b = bbase[gid>>8];
  int4 v = *(int4*)(off + gid*4);
  v.x+=b; v.y+=b; v.z+=b; v.w+=b;
  *(int4*)(off + gid*4)=v;
}

// ---------------------------------------------------------------- reorder (2-pass)
__global__ __launch_bounds__(256) void k_reorder1(const float* kt, int* off, int* srcIdx){
  int m = blockIdx.x*256+threadIdx.x;
  float kx=kt[2*m], ky=kt[2*m+1];
  int ix=((int)floorf(kx*1024.f))&1023;
  int iy=((int)floorf(ky*1024.f))&1023;
  int pos = atomicAdd(&off[(ix<<10)|iy],1);
  srcIdx[pos]=m;
}

__global__ __launch_bounds__(256) void k_reorder2(const int* __restrict__ srcIdx, const float* __restrict__ kt,
                                                  const float* __restrict__ kre, const float* __restrict__ kim,
                                                  float4* __restrict__ pd, const float* __restrict__ t){
  int p = blockIdx.x*256+threadIdx.x;
  int m = srcIdx[p];
  float kx=kt[2*m], ky=kt[2*m+1];
  float gx=kx*1024.f, gy=ky*1024.f;
  float tx=gx-floorf(gx), ty=gy-floorf(gy);
  float dx=kx-0.5f, dy=ky-0.5f;
  float r=sqrtf(dx*dx+dy*dy);
  float dcf=sqrtf(r/(t[15]+1e-8f));
  pd[p]=make_float4(tx,ty,kre[m]*dcf,kim[m]*dcf);
}

// ---------------------------------------------------------------- half-pack helper
__device__ __forceinline__ void store_h4(__half* dst, const float v[4]){
  __half h0=__float2half(v[0]), h1=__float2half(v[1]),
         h2=__float2half(v[2]), h3=__float2half(v[3]);
  short4 s;
  s.x=*(short*)&h0; s.y=*(short*)&h1; s.z=*(short*)&h2; s.w=*(short*)&h3;
  *(short4*)dst=s;
}

// ---------------------------------------------------------------- build T planes (fp16) + Gy
__global__ __launch_bounds__(256) void k_mkWG(const float4* __restrict__ pd,
                                              const int* __restrict__ off,
                                              __half* __restrict__ WpH,
                                              float2* __restrict__ Gy){
  int gid=blockIdx.x*256+threadIdx.x;
  int r=gid>>8, c0=(gid&255)<<2;
  float w00[4],wE[4],wS[4],wSE[4],wSW[4],gx[4],gy[4];
#pragma unroll
  for(int q=0;q<4;q++){ w00[q]=0.f;wE[q]=0.f;wS[q]=0.f;wSE[q]=0.f;wSW[q]=0.f;gx[q]=0.f;gy[q]=0.f; }
#pragma unroll
  for(int dr=0;dr<2;dr++){
    int br=(r-dr)&1023;
    int rowbase=br<<10;
    if (c0>0){
      int O[6];
#pragma unroll
      for(int q=0;q<6;q++) O[q]=off[rowbase+c0-2+q];
#pragma unroll
      for(int i=0;i<5;i++){
        for(int j=O[i]; j<O[i+1]; j++){
          float4 p=pd[j];
          float wx = dr? p.x : 1.f-p.x;
          float uy=1.f-p.y, vy=p.y;
          float a0=wx*uy, a1=wx*vy;
          float wpu=p.x*uy, wpv=p.x*vy;
          if (i>=1){
            w00[i-1]=fmaf(a0,a0,w00[i-1]);
            wE [i-1]=fmaf(a0,a1,wE [i-1]);
            gx [i-1]=fmaf(a0,p.z,gx[i-1]); gy[i-1]=fmaf(a0,p.w,gy[i-1]);
            if(!dr){ wS[i-1]=fmaf(a0,wpu,wS[i-1]); wSE[i-1]=fmaf(a0,wpv,wSE[i-1]); }
          }
          if (i<=3){
            w00[i]=fmaf(a1,a1,w00[i]);
            gx [i]=fmaf(a1,p.z,gx[i]); gy[i]=fmaf(a1,p.w,gy[i]);
            if(!dr){ wS[i]=fmaf(a1,wpv,wS[i]); wSW[i]=fmaf(a1,wpu,wSW[i]); }
          }
        }
      }
    } else {
      int bw=rowbase+1023;
      int sw=off[bw-1], ew=off[bw];
      for(int j=sw;j<ew;j++){
        float4 p=pd[j];
        float wx = dr? p.x : 1.f-p.x;
        float uy=1.f-p.y, vy=p.y;
        float a1=wx*vy;
        w00[0]=fmaf(a1,a1,w00[0]);
        gx [0]=fmaf(a1,p.z,gx[0]); gy[0]=fmaf(a1,p.w,gy[0]);
        if(!dr){ float wpu=p.x*uy, wpv=p.x*vy;
          wS[0]=fmaf(a1,wpv,wS[0]); wSW[0]=fmaf(a1,wpu,wSW[0]); }
      }
      int O[5];
      O[0]=(rowbase==0)?0:off[rowbase-1];
#pragma unroll
      for(int q=1;q<5;q++) O[q]=off[rowbase+q-1];
#pragma unroll
      for(int i=0;i<4;i++){
        for(int j=O[i]; j<O[i+1]; j++){
          float4 p=pd[j];
          float wx = dr? p.x : 1.f-p.x;
          float uy=1.f-p.y, vy=p.y;
          float a0=wx*uy, a1=wx*vy;
          float wpu=p.x*uy, wpv=p.x*vy;
          w00[i]=fmaf(a0,a0,w00[i]);
          wE [i]=fmaf(a0,a1,wE [i]);
          gx [i]=fmaf(a0,p.z,gx[i]); gy[i]=fmaf(a0,p.w,gy[i]);
          if(!dr){ wS[i]=fmaf(a0,wpu,wS[i]); wSE[i]=fmaf(a0,wpv,wSE[i]); }
          if (i<=2){
            w00[i+1]=fmaf(a1,a1,w00[i+1]);
            gx [i+1]=fmaf(a1,p.z,gx[i+1]); gy[i+1]=fmaf(a1,p.w,gy[i+1]);
            if(!dr){ wS[i+1]=fmaf(a1,wpv,wS[i+1]); wSW[i+1]=fmaf(a1,wpu,wSW[i+1]); }
          }
        }
      }
    }
  }
  size_t base=((size_t)r<<10)+c0;
  store_h4(&WpH[base],               w00);
  store_h4(&WpH[(size_t)HW_+base],   wE );
  store_h4(&WpH[(size_t)2*HW_+base], wS );
  store_h4(&WpH[(size_t)3*HW_+base], wSE);
  store_h4(&WpH[(size_t)4*HW_+base], wSW);
#pragma unroll
  for(int q=0;q<4;q++) Gy[base+q]=make_float2(gx[q],gy[q]);
}

// ---------------------------------------------------------------- 9-tap symmetric stencil (fp16 weights)
__device__ __forceinline__ float2 t_tap_p(const float2* __restrict__ Fm, const float2* __restrict__ F0,
                                          const float2* __restrict__ Fp, const __half* __restrict__ WpH,
                                          int rowW, int rowWm, int c){
  int cm=(c+1023)&1023, cp=(c+1)&1023;
  const __half* W00=WpH;
  const __half* WE =WpH+(size_t)HW_;
  const __half* WS =WpH+(size_t)2*HW_;
  const __half* WSE=WpH+(size_t)3*HW_;
  const __half* WSW=WpH+(size_t)4*HW_;
  float2 f=F0[c];
  float w=__half2float(W00[rowW+c]);
  float ux=w*f.x, uy=w*f.y;
  f=F0[cp]; w=__half2float(WE [rowW +c ]); ux=fmaf(w,f.x,ux); uy=fmaf(w,f.y,uy);  // +E
  f=F0[cm]; w=__half2float(WE [rowW +cm]); ux=fmaf(w,f.x,ux); uy=fmaf(w,f.y,uy);  // -E
  f=Fp[c ]; w=__half2float(WS [rowW +c ]); ux=fmaf(w,f.x,ux); uy=fmaf(w,f.y,uy);  // +S
  f=Fm[c ]; w=__half2float(WS [rowWm+c ]); ux=fmaf(w,f.x,ux); uy=fmaf(w,f.y,uy);  // -S
  f=Fp[cp]; w=__half2float(WSE[rowW +c ]); ux=fmaf(w,f.x,ux); uy=fmaf(w,f.y,uy);  // +SE
  f=Fm[cm]; w=__half2float(WSE[rowWm+cm]); ux=fmaf(w,f.x,ux); uy=fmaf(w,f.y,uy);  // -SE
  f=Fp[cm]; w=__half2float(WSW[rowW +c ]); ux=fmaf(w,f.x,ux); uy=fmaf(w,f.y,uy);  // +SW
  f=Fm[cp]; w=__half2float(WSW[rowWm+cp]); ux=fmaf(w,f.x,ux); uy=fmaf(w,f.y,uy);  // -SW
  return make_float2(ux,uy);
}

// ---------------------------------------------------------------- Tinit device fn (S_1 = 1024 * T(:,DC))
__device__ __forceinline__ void dev_Tinit(int r, int tid, float2* __restrict__ S,
                                          const __half* __restrict__ WpH, float* pb, float* sm4){
  float nsq=0.f;
  float2* row = S + ((size_t)r<<10);
#pragma unroll
  for(int q=0;q<4;q++){
    int c=tid+256*q;
    float val=0.f;
    if (r==0){
      if (c==0) val=__half2float(WpH[0]);
      else if (c==1) val=__half2float(WpH[(size_t)HW_]);
      else if (c==1023) val=__half2float(WpH[(size_t)HW_+1023]);
    } else if (r==1){
      if (c==0) val=__half2float(WpH[(size_t)2*HW_]);
      else if (c==1) val=__half2float(WpH[(size_t)3*HW_]);
      else if (c==1023) val=__half2float(WpH[(size_t)4*HW_]);
    } else if (r==1023){
      if (c==0) val=__half2float(WpH[(size_t)2*HW_+(1023<<10)]);
      else if (c==1) val=__half2float(WpH[(size_t)4*HW_+(1023<<10)+1]);
      else if (c==1023) val=__half2float(WpH[(size_t)3*HW_+(1023<<10)+1023]);
    }
    val *= 1024.f;
    row[c]=make_float2(val,0.f);
    nsq=fmaf(val,val,nsq);
  }
  for(int o=32;o>0;o>>=1) nsq+=__shfl_down(nsq,o,64);
  if((tid&63)==0) sm4[tid>>6]=nsq;
  __syncthreads();
  if(tid==0) pb[r]=sm4[0]+sm4[1]+sm4[2]+sm4[3];
}

__global__ __launch_bounds__(256) void k_Tinit(float2* S, const __half* WpH, float* pb){
  __shared__ float sm4[4];
  dev_Tinit(ROWSWZ(blockIdx.x), threadIdx.x, S, WpH, pb, sm4);
}

// ---------------------------------------------------------------- classic fused double power step (fallback path)
__global__ __launch_bounds__(256) void k_Tpow2(const float2* __restrict__ Sin, float2* __restrict__ Sout,
    const __half* __restrict__ WpH, const float* __restrict__ pbIn, float* __restrict__ pbOut){
  __shared__ __align__(16) float2 mid[3][1024];
  __shared__ float smr[4];
  int tid=threadIdx.x;
  int r=ROWSWZ(blockIdx.x);
  float s=0.f;
  for(int k=tid;k<1024;k+=256) s+=pbIn[k];
  for(int o=32;o>0;o>>=1) s+=__shfl_down(s,o,64);
  if((tid&63)==0) smr[tid>>6]=s;
  __syncthreads();
  float sc=1.f/(sqrtf(smr[0]+smr[1]+smr[2]+smr[3])+1e-12f);
  for(int dm=0;dm<3;dm++){
    int m=(r+dm+1023)&1023;
    int mm=(m+1023)&1023, mp=(m+1)&1023;
    int rowW=m<<10, rowWm=mm<<10;
    const float2* Rm=Sin+((size_t)mm<<10);
    const float2* R0=Sin+((size_t)m <<10);
    const float2* Rp=Sin+((size_t)mp<<10);
#pragma unroll
    for(int q=0;q<4;q++){
      int c=tid+256*q;
      float2 u=t_tap_p(Rm,R0,Rp,WpH,rowW,rowWm,c);
      mid[dm][c]=make_float2(u.x*sc,u.y*sc);
    }
  }
  __syncthreads();
  int rm=(r+1023)&1023;
  int rowW=r<<10, rowWm=rm<<10;
  float nsq=0.f;
  float2 outv[4];
#pragma unroll
  for(int q=0;q<4;q++){
    int c=tid+256*q;
    float2 u=t_tap_p(&mid[0][0],&mid[1][0],&mid[2][0],WpH,rowW,rowWm,c);
    nsq=fmaf(u.x,u.x,fmaf(u.y,u.y,nsq));
    outv[q]=u;
  }
  float2* orow=Sout+((size_t)r<<10);
#pragma unroll
  for(int q=0;q<4;q++) orow[tid+256*q]=outv[q];
  for(int o=32;o>0;o>>=1) nsq+=__shfl_down(nsq,o,64);
  if((tid&63)==0) smr[tid>>6]=nsq;
  __syncthreads();
  if(tid==0) pbOut[r]=smr[0]+smr[1]+smr[2]+smr[3];
}

// ---------------------------------------------------------------- single power step, sc given (mega) / computed (classic)
// S_out = sc*T(S_in); pbOut[r]=row ||.||^2; if last: pa[r]=row dot(S_in,T S_in), t[0]=sc t[1]=||S_in||^2
__device__ __forceinline__ void dev_TpowStep(int r, int tid, const float2* __restrict__ Sin,
    float2* __restrict__ Sout, const __half* __restrict__ WpH, float sc, float bIn,
    float* pbOut, float* pa, float* t, int last, float2 (*Fsm)[1024], float* smr){
  int rm=(r+1023)&1023, rp=(r+1)&1023;
  {
    const float4* s0=(const float4*)(Sin+((size_t)rm<<10));
    const float4* s1=(const float4*)(Sin+((size_t)r <<10));
    const float4* s2=(const float4*)(Sin+((size_t)rp<<10));
    float4* f0=(float4*)Fsm[0]; float4* f1=(float4*)Fsm[1]; float4* f2=(float4*)Fsm[2];
    for(int p2=tid;p2<512;p2+=256){ f0[p2]=s0[p2]; f1[p2]=s1[p2]; f2[p2]=s2[p2]; }
  }
  __syncthreads();
  if (last && r==0 && tid==0){ t[0]=sc; t[1]=bIn; }
  int rowW=r<<10, rowWm=rm<<10;
  float dotp=0.f, nsq=0.f;
  float2 outv[4];
#pragma unroll
  for(int q=0;q<4;q++){
    int c=tid+256*q;
    float2 u=t_tap_p(&Fsm[0][0],&Fsm[1][0],&Fsm[2][0],WpH,rowW,rowWm,c);
    float2 fC=Fsm[1][c];
    dotp=fmaf(fC.x,u.x,fmaf(fC.y,u.y,dotp));
    float ox=u.x*sc, oy=u.y*sc;
    nsq=fmaf(ox,ox,fmaf(oy,oy,nsq));
    outv[q]=make_float2(ox,oy);
  }
  float2* orow=Sout+((size_t)r<<10);
#pragma unroll
  for(int q=0;q<4;q++) orow[tid+256*q]=outv[q];
  for(int o=32;o>0;o>>=1){ dotp+=__shfl_down(dotp,o,64); nsq+=__shfl_down(nsq,o,64); }
  __syncthreads();
  if((tid&63)==0){ smr[tid>>6]=dotp; smr[4+(tid>>6)]=nsq; }
  __syncthreads();
  if(tid==0){ if(last) pa[r]=smr[0]+smr[1]+smr[2]+smr[3]; pbOut[r]=smr[4]+smr[5]+smr[6]+smr[7]; }
}

__global__ __launch_bounds__(256) void k_Tpow(const float2* __restrict__ Sin, float2* __restrict__ Sout,
    const __half* __restrict__ WpH, const float* __restrict__ pbIn,
    float* pbOut, float* pa, float* t){
  __shared__ __align__(16) float2 Fsm[3][1024];
  __shared__ float smr[8];
  int tid=threadIdx.x;
  float s=0.f;
  for(int k=tid;k<1024;k+=256) s+=pbIn[k];
  for(int o=32;o>0;o>>=1) s+=__shfl_down(s,o,64);
  if((tid&63)==0) smr[tid>>6]=s;
  __syncthreads();
  float b=smr[0]+smr[1]+smr[2]+smr[3];
  float sc=1.f/(sqrtf(b)+1e-12f);
  __syncthreads();
  dev_TpowStep(ROWSWZ(blockIdx.x), tid, Sin, Sout, WpH, sc, b, pbOut, pa, t, 1, Fsm, smr);
}

// ---------------------------------------------------------------- Tfinal
__device__ __forceinline__ void dev_Tfinal(int tid, const float* __restrict__ pa,
                                           const float* __restrict__ wraw, float* t, float* sm4){
  float s=0.f;
  for(int k=tid;k<1024;k+=256) s+=pa[k];
  for(int o=32;o>0;o>>=1) s+=__shfl_down(s,o,64);
  if((tid&63)==0) sm4[tid>>6]=s;
  __syncthreads();
  if(tid==0){
    float raw=sm4[0]+sm4[1]+sm4[2]+sm4[3];
    float sc=t[0], b=t[1];
    float a=sc*sc*raw;            // ||av_10||^2
    float vn=sqrtf(b)*sc;         // ||v_9||
    float opn=sqrtf(a)/(vn+1e-12f);
    float sig=1.f/(1.f+__expf(-wraw[0]));
    t[19]=2.f*sig/(opn*opn);
  }
}

__global__ __launch_bounds__(256) void k_Tfinal(const float* pa, const float* wraw, float* t){
  __shared__ float sm4[4];
  dev_Tfinal(threadIdx.x, pa, wraw, t, sm4);
}

// ---------------------------------------------------------------- Tsub + rowIFFT device fn
__device__ __forceinline__ void dev_Tsub(int unit, int tid, const float2* __restrict__ Fin,
    const __half* __restrict__ WpH, const float2* __restrict__ Gy,
    float2* __restrict__ G2, float scale, void* smemv){
  float2 (*Fsm)[1024] = (float2(*)[1024])smemv;
  int r=ROWSWZ(unit);
  int rm=(r+1023)&1023, rp=(r+1)&1023;
  {
    const float4* s0=(const float4*)(Fin+((size_t)rm<<10));
    const float4* s1=(const float4*)(Fin+((size_t)r <<10));
    const float4* s2=(const float4*)(Fin+((size_t)rp<<10));
    float4* f0=(float4*)Fsm[0]; float4* f1=(float4*)Fsm[1]; float4* f2=(float4*)Fsm[2];
    for(int p2=tid;p2<512;p2+=256){ f0[p2]=s0[p2]; f1[p2]=s1[p2]; f2[p2]=s2[p2]; }
  }
  __syncthreads();
  int rowW=r<<10, rowWm=rm<<10;
  float2 v[4];
  const float2* gyr=Gy+((size_t)r<<10);
#pragma unroll
  for(int q=0;q<4;q++){
    int c=tid+256*q;
    float2 u=t_tap_p(&Fsm[0][0],&Fsm[1][0],&Fsm[2][0],WpH,rowW,rowWm,c);
    float2 gy=gyr[c];
    v[q]=make_float2(u.x-gy.x,u.y-gy.y);
  }
  __syncthreads();                          // all Fsm reads done before aliasing
  float2* A=(float2*)smemv; float2* B=A+1088;
  fft1024_core<1>(v,tid,A,B,scale);
  float2* d=G2+((size_t)r<<10);
#pragma unroll
  for(int rr=0;rr<4;rr++) d[tid+256*rr]=v[rr];
}

__global__ __launch_bounds__(256) void k_Tsub_fft(const float2* Fin, const __half* WpH,
                                                  const float2* Gy, float2* G2, float scale){
  __shared__ __align__(16) char smem[24576];
  dev_Tsub(blockIdx.x, threadIdx.x, Fin, WpH, Gy, G2, scale, smem);
}

// ---------------------------------------------------------------- composed-conv tables
__global__ __launch_bounds__(256) void k_mkE(const float* w1, const float* b1,
                                             const float* w2, const float* b2, float* ec){
  __shared__ float sw1[576], sw2[576], sb1[32], sB[324];
  int tid=threadIdx.x;
  for(int p=tid;p<576;p+=256){ sw1[p]=w1[p]; sw2[p]=w2[p]; }
  if(tid<32) sb1[tid]=b1[tid];
  __syncthreads();
  for(int e=tid;e<324;e+=256){
    int oc=e/162, r=e-oc*162, u=r/18, r2=r-u*18, ic=r2/9, v=r2-ic*9;
    float s=0.f;
    for(int cm=0;cm<32;cm++) s=fmaf(sw2[oc*288+cm*9+u], sw1[cm*18+ic*9+v], s);
    sB[e]=s; ec[120+e]=s;
  }
  if(tid<18){
    int oc=tid/9, u=tid-oc*9;
    float s=0.f;
    for(int cm=0;cm<32;cm++) s=fmaf(sw2[oc*288+cm*9+u], sb1[cm], s);
    ec[102+tid]=s;
  }
  if(tid<2){
    float s=b2[tid];
    for(int u=0;u<9;u++){
      float bb=0.f;
      for(int cm=0;cm<32;cm++) bb=fmaf(sw2[tid*288+cm*9+u], sb1[cm], bb);
      s+=bb;
    }
    ec[100+tid]=s;
    ec[444+tid]=b2[tid];
  }
  __syncthreads();
  if(tid<100){
    int oc=tid/50, r=tid-oc*50, ic=r/25, r2=r-ic*25, dy=r2/5, dx=r2-dy*5;
    float s=0.f;
    for(int uy=0;uy<3;uy++){ int vy=dy-uy; if(vy<0||vy>2) continue;
      for(int ux=0;ux<3;ux++){ int vx=dx-ux; if(vx<0||vx>2) continue;
        s+=sB[oc*162+(uy*3+ux)*18+ic*9+vy*3+vx];
      }
    }
    ec[tid]=s;
  }
}

// ---------------------------------------------------------------- fused 5x5 composed CNN + update (device fn)
#define CT_S 41
__device__ void dev_cnn5(int u, int tid, const float2* __restrict__ x, const float2* __restrict__ res,
    const float* __restrict__ ec, const float* __restrict__ t,
    float2* __restrict__ xout, float* __restrict__ outPlanar, float* sm){
  if (u>=1024){
    // ---- border ring: exact conv2(conv1) with h zero-masked outside image
    int id = (u-1024)*256+tid;   // 4096
    int py,px;
    if (id<1024){ py=0; px=id; }
    else if(id<2048){ py=1023; px=id-1024; }
    else if(id<3072){ py=id-2048; px=0; }
    else { py=id-3072; px=1023; }
    float s0=ec[444], s1=ec[445];
    for(int uy=0;uy<3;uy++){
      int qy=py+uy-1; if((unsigned)qy>=1024u) continue;
      for(int ux=0;ux<3;ux++){
        int qx=px+ux-1; if((unsigned)qx>=1024u) continue;
        int uu=uy*3+ux;
        s0+=ec[102+uu]; s1+=ec[111+uu];
        const float* B0=&ec[120+uu*18];
        const float* B1=&ec[282+uu*18];
        for(int vy=0;vy<3;vy++){
          int sy2=qy+vy-1; if((unsigned)sy2>=1024u) continue;
          for(int vx=0;vx<3;vx++){
            int sx2=qx+vx-1; if((unsigned)sx2>=1024u) continue;
            int v=vy*3+vx;
            float2 xv=x[(size_t)sy2*W_+sx2];
            s0 = fmaf(B0[v],xv.x,fmaf(B0[9+v],xv.y,s0));
            s1 = fmaf(B1[v],xv.x,fmaf(B1[9+v],xv.y,s1));
          }
        }
      }
    }
    float wreg=t[19];
    size_t base=(size_t)py*W_+px;
    float2 xv=x[base], rv=res[base];
    float o0=xv.x - wreg*rv.x - s0;
    float o1=xv.y - wreg*rv.y - s1;
    if (outPlanar){ outPlanar[base]=o0; outPlanar[HW_+base]=o1; }
    else          { xout[base]=make_float2(o0,o1); }
    return;
  }
  float* xt0=sm;           // 36*CT_S = 1476
  float* xt1=sm+1476;
  float* sE =sm+2952;      // 102
  int by=u>>5, bx=u&31;
  int ty0=by<<5, tx0=bx<<5;
  for(int p=tid;p<102;p+=256) sE[p]=ec[p];
  for(int p=tid;p<1296;p+=256){
    int r=p/36, c=p-r*36;
    int gy=ty0-2+r, gx=tx0-2+c;
    float vx=0.f, vy=0.f;
    if((unsigned)gy<1024u && (unsigned)gx<1024u){ float2 v=x[(size_t)gy*W_+gx]; vx=v.x; vy=v.y; }
    xt0[r*CT_S+c]=vx; xt1[r*CT_S+c]=vy;
  }
  __syncthreads();
  int row=tid>>3, c4=(tid&7)<<2;
  float a0[4], a1[4];
  float C00=sE[100], C01=sE[101];
#pragma unroll
  for(int jj=0;jj<4;jj++){ a0[jj]=C00; a1[jj]=C01; }
#pragma unroll
  for(int dy=0;dy<5;dy++){
    const float* r0=&xt0[(row+dy)*CT_S+c4];
    const float* r1=&xt1[(row+dy)*CT_S+c4];
    float f0[9], f1[9];
#pragma unroll
    for(int q=0;q<9;q++){ f0[q]=r0[q]; f1[q]=r1[q]; }
#pragma unroll
    for(int dx=0;dx<5;dx++){
      float e00=sE[dy*5+dx], e01=sE[25+dy*5+dx];
      float e10=sE[50+dy*5+dx], e11=sE[75+dy*5+dx];
#pragma unroll
      for(int jj=0;jj<4;jj++){
        a0[jj]=fmaf(e00,f0[jj+dx],fmaf(e01,f1[jj+dx],a0[jj]));
        a1[jj]=fmaf(e10,f0[jj+dx],fmaf(e11,f1[jj+dx],a1[jj]));
      }
    }
  }
  int py=ty0+row;
  float wreg = t[19];
  size_t base=(size_t)py*W_ + tx0 + c4;
  bool rowEdge = (py==0)||(py==1023);
  if (outPlanar){
#pragma unroll
    for(int jj=0;jj<4;jj++){
      int px=tx0+c4+jj;
      if (rowEdge || px==0 || px==1023) continue;
      float2 rv=res[base+jj];
      float xr_=xt0[(row+2)*CT_S+c4+jj+2];
      float xi_=xt1[(row+2)*CT_S+c4+jj+2];
      outPlanar[base+jj]      = xr_ - wreg*rv.x - a0[jj];
      outPlanar[HW_+base+jj]  = xi_ - wreg*rv.y - a1[jj];
    }
  } else {
#pragma unroll
    for(int jj=0;jj<4;jj++){
      int px=tx0+c4+jj;
      if (rowEdge || px==0 || px==1023) continue;
      float2 rv=res[base+jj];
      float xr_=xt0[(row+2)*CT_S+c4+jj+2];
      float xi_=xt1[(row+2)*CT_S+c4+jj+2];
      xout[base+jj]=make_float2(xr_ - wreg*rv.x - a0[jj],
                                xi_ - wreg*rv.y - a1[jj]);
    }
  }
}

__global__ __launch_bounds__(256) void k_cnn5(const float2* x, const float2* res,
    const float* ec, const float* t, float2* xout, float* outPlanar){
  __shared__ float sm[3054];
  dev_cnn5(blockIdx.x, threadIdx.x, x, res, ec, t, xout, outPlanar, sm);
}

// ================================================================ cooperative mega-kernel
struct MA {
  float2 *Wx0, *Wx1, *WF, *G2, *Gy;
  const __half* WpH;
  float* t; const float* ec;
  float *pa, *pb0, *pb1;
  float* out; const float* wraw;
};

__global__ __launch_bounds__(256,4) void k_mega(MA a){
  cg::grid_group grid = cg::this_grid();
  __shared__ __align__(16) char smem[24576];
  __shared__ float smr[8];
  int tid=threadIdx.x;
  int nb=gridDim.x, bid=blockIdx.x;
  float2* A=(float2*)smem; float2* B=A+1088;
  float2 (*Fsm)[1024] = (float2(*)[1024])smem;

  // ---- power: Tinit (S0=WF)
  for(int u=bid;u<1024;u+=nb){
    dev_Tinit(ROWSWZ(u), tid, a.WF, a.WpH, a.pb0, smr);
    __syncthreads();
  }
  grid.sync();
  // ---- 9 power steps
  for(int n=0;n<9;n++){
    const float2* si = (n&1)? a.G2 : a.WF;
    float2*       so = (n&1)? a.WF : a.G2;
    const float*  pi = (n&1)? a.pb1 : a.pb0;
    float*        po = (n&1)? a.pb0 : a.pb1;
    float s=0.f;
    for(int k=tid;k<1024;k+=256) s+=pi[k];
    for(int o=32;o>0;o>>=1) s+=__shfl_down(s,o,64);
    if((tid&63)==0) smr[tid>>6]=s;
    __syncthreads();
    float b=smr[0]+smr[1]+smr[2]+smr[3];
    float sc=1.f/(sqrtf(b)+1e-12f);
    __syncthreads();
    int last=(n==8);
    for(int u=bid;u<1024;u+=nb){
      dev_TpowStep(ROWSWZ(u), tid, si, so, a.WpH, sc, b, po, a.pa, a.t, last, Fsm, smr);
      __syncthreads();
    }
    grid.sync();
  }
  // ---- Tfinal (block 0)
  if(bid==0) dev_Tfinal(tid, a.pa, a.wraw, a.t, smr);
  grid.sync();
  // ---- npcg = 4 PGD iterations
  for(int it=0; it<4; ++it){
    float2* xin  = (it&1)? a.Wx1 : a.Wx0;
    float2* xout = (it&1)? a.Wx0 : a.Wx1;
    float* planar = (it==3)? a.out : (float*)nullptr;
    for(int u=bid;u<1024;u+=nb){ dev_fft_row<-1>(u,tid,xin,a.WF,SC_,A,B); __syncthreads(); }
    grid.sync();
    for(int u=bid;u<1024;u+=nb){ dev_fft_col<-1>(u,tid,a.WF,SC_,A,B); __syncthreads(); }
    grid.sync();
    for(int u=bid;u<1024;u+=nb){ dev_Tsub(u,tid,a.WF,a.WpH,a.Gy,a.G2,SC_,smem); __syncthreads(); }
    grid.sync();
    for(int u=bid;u<1024;u+=nb){ dev_fft_col<1>(u,tid,a.G2,SC_,A,B); __syncthreads(); }
    grid.sync();
    for(int u=bid;u<1040;u+=nb){ dev_cnn5(u,tid,xin,a.G2,a.ec,a.t,xout,planar,(float*)smem); __syncthreads(); }
    grid.sync();
  }
}

// ================================================================ launch
extern "C" void kernel_launch(void* const* d_in, const int* in_sizes, int n_in,
                              void* d_out, int out_size, void* d_ws, size_t ws_size,
                              hipStream_t stream){
  (void)in_sizes; (void)n_in; (void)out_size; (void)ws_size;
  const float* xr  =(const float*)d_in[0];
  const float* xi  =(const float*)d_in[1];
  const float* kre =(const float*)d_in[2];
  const float* kim =(const float*)d_in[3];
  const float* kt  =(const float*)d_in[4];
  const float* wraw=(const float*)d_in[5];
  const float* w1  =(const float*)d_in[6];
  const float* b1  =(const float*)d_in[7];
  const float* w2  =(const float*)d_in[8];
  const float* b2  =(const float*)d_in[9];
  float* out = (float*)d_out;

  char* ws=(char*)d_ws;
  float2* Wx0 =(float2*)(ws);                      // 8MB
  float2* Wx1 =(float2*)(ws + ((size_t) 8<<20));   // 8MB
  int*   counts=(int*)  (ws + ((size_t) 8<<20));   // 4MB alias of Wx1 (setup only)
  int*   srcIdx=(int*)  (ws + ((size_t)12<<20));   // 2MB alias of Wx1 tail (setup only)
  float2* WF  =(float2*)(ws + ((size_t)16<<20));   // 8MB  fwd-FFT grid / power ping S0
  float4* pd  =(float4*)(ws + ((size_t)24<<20));   // 8MB  sorted point data
  float2* G2  =(float2*)(ws + ((size_t)32<<20));   // 8MB  residual grid / power pong S1
  int*  off   =(int*)   (ws + ((size_t)40<<20));   // 4MB  CSR ends
  float2* Gy  =(float2*)(ws + ((size_t)44<<20));   // 8MB  Grid(y*sqrt_dcf)
  __half* WpH =(__half*)(ws + ((size_t)52<<20));   // 10MB 5 stencil planes (fp16)
  float2* S0  = WF;
  float2* S1  = G2;
  int*  bsum  =(int*)   (ws + ((size_t)62<<20));            // 4KB
  float* t    =(float*) (ws + ((size_t)62<<20) + 8192);
  float* ec   =(float*) (ws + ((size_t)62<<20) + 16384);
  float* pa   =(float*) (ws + ((size_t)62<<20) + 32768);    // 4KB
  float* pb0  =(float*) (ws + ((size_t)62<<20) + 40960);    // 4KB
  float* pb1  =(float*) (ws + ((size_t)62<<20) + 49152);    // 4KB
  float* pmax =(float*) (ws + ((size_t)62<<20) + 57344);    // 8KB

  // ---- setup (classic)
  k_pack<<<HW_/256,256,0,stream>>>(xr,xi,Wx0,t);
  k_mkE<<<1,256,0,stream>>>(w1,b1,w2,b2,ec);
  hipMemsetAsync(counts,0,(size_t)HW_*sizeof(int),stream);
  k_hist<<<M_/256,256,0,stream>>>(kt,counts,pmax);
  k_reduce_max<<<1,256,0,stream>>>(pmax,t);
  k_scan1<<<1024,256,0,stream>>>(counts,off,bsum);
  k_scan2<<<1,256,0,stream>>>(bsum);
  k_scan3<<<1024,256,0,stream>>>(off,bsum);
  k_reorder1<<<M_/256,256,0,stream>>>(kt,off,srcIdx);
  k_reorder2<<<M_/256,256,0,stream>>>(srcIdx,kt,kre,kim,pd,t);
  k_mkWG<<<HW_/1024,256,0,stream>>>(pd,off,WpH,Gy);

  // ---- coop capability probe (host-side queries only; cached)
  static int s_coop = -1;
  static int s_grid = 0;
  if (s_coop < 0){
    s_coop = 0;
    int attr=0;
    if (hipDeviceGetAttribute(&attr, hipDeviceAttributeCooperativeLaunch, 0)==hipSuccess && attr){
      int maxB=0;
      if (hipOccupancyMaxActiveBlocksPerMultiprocessor(&maxB, k_mega, 256, 0)==hipSuccess && maxB>0){
        hipDeviceProp_t prop;
        if (hipGetDeviceProperties(&prop, 0)==hipSuccess){
          int g = maxB * prop.multiProcessorCount;
          if (g >= 64){ s_coop = 1; s_grid = (g>1024)?1024:g; }
        }
      }
    }
  }

  bool done=false;
  if (s_coop==1){
    MA ma;
    ma.Wx0=Wx0; ma.Wx1=Wx1; ma.WF=WF; ma.G2=G2; ma.Gy=Gy; ma.WpH=WpH;
    ma.t=t; ma.ec=ec; ma.pa=pa; ma.pb0=pb0; ma.pb1=pb1; ma.out=out; ma.wraw=wraw;
    void* args[] = { (void*)&ma };
    hipError_t e = hipLaunchCooperativeKernel((const void*)k_mega, dim3(s_grid), dim3(256),
                                              args, 0, stream);
    if (e == hipSuccess) done = true;
    else s_coop = 0;   // never retry
  }

  if (!done){
    // ---- classic fallback (r3-proven sequence)
    k_Tinit<<<H_,256,0,stream>>>(S0,WpH,pb0);
    k_Tpow2<<<H_,256,0,stream>>>(S0,S1,WpH,pb0,pb1);   // apps 2-3
    k_Tpow2<<<H_,256,0,stream>>>(S1,S0,WpH,pb1,pb0);   // apps 4-5
    k_Tpow2<<<H_,256,0,stream>>>(S0,S1,WpH,pb0,pb1);   // apps 6-7
    k_Tpow2<<<H_,256,0,stream>>>(S1,S0,WpH,pb1,pb0);   // apps 8-9
    k_Tpow <<<H_,256,0,stream>>>(S0,S1,WpH,pb0,pb1,pa,t);  // app 10
    k_Tfinal<<<1,256,0,stream>>>(pa,wraw,t);
    for (int it=0; it<4; it++){
      float2* xin  = (it&1)? Wx1 : Wx0;
      float2* xout = (it&1)? Wx0 : Wx1;
      float* planar = (it==3)? out : (float*)nullptr;
      k_fft_rows<-1><<<H_,256,0,stream>>>(xin,WF,SC_);
      k_fft_cols1<-1><<<H_,256,0,stream>>>(WF,SC_);
      k_Tsub_fft<<<H_,256,0,stream>>>(WF,WpH,Gy,G2,SC_);
      k_fft_cols1<1><<<H_,256,0,stream>>>(G2,SC_);
      k_cnn5<<<1040,256,0,stream>>>(xin,G2,ec,t,xout,planar);
    }
  }
}

// Round 5
// 498.125 us; speedup vs baseline: 4.8214x; 4.8214x over previous
//
#include <hip/hip_runtime.h>

#define H_  1024
#define W_  1024
#define HW_ (H_*W_)
#define M_  524288

#define SWZ(a) ((a) + ((a)>>4))

// ---------------------------------------------------------------- complex mul
__device__ __forceinline__ float2 cmulf(float2 a, float2 b){
  return make_float2(fmaf(a.x,b.x,-(a.y*b.y)), fmaf(a.x,b.y,a.y*b.x));
}

// ---------------------------------------------------------------- radix-4 bfly
template<int DIR>
__device__ __forceinline__ void bfly4(float2 v[4], int j, int Ns){
  if (Ns>1){
    float ang = ((DIR>0)?6.28318530717958647692f:-6.28318530717958647692f)
                * (float)(j&(Ns-1)) / (float)(4*Ns);
    float s,c; __sincosf(ang,&s,&c);
    float2 w1=make_float2(c,s);
    float2 w2=cmulf(w1,w1);
    float2 w3=cmulf(w2,w1);
    v[1]=cmulf(v[1],w1); v[2]=cmulf(v[2],w2); v[3]=cmulf(v[3],w3);
  }
  float2 t0=make_float2(v[0].x+v[2].x, v[0].y+v[2].y);
  float2 t2=make_float2(v[0].x-v[2].x, v[0].y-v[2].y);
  float2 t1=make_float2(v[1].x+v[3].x, v[1].y+v[3].y);
  float2 t3=make_float2(v[1].x-v[3].x, v[1].y-v[3].y);
  float2 t3r=(DIR<0)?make_float2(t3.y,-t3.x):make_float2(-t3.y,t3.x);
  v[0]=make_float2(t0.x+t1.x,  t0.y+t1.y);
  v[1]=make_float2(t2.x+t3r.x, t2.y+t3r.y);
  v[2]=make_float2(t0.x-t1.x,  t0.y-t1.y);
  v[3]=make_float2(t2.x-t3r.x, t2.y-t3r.y);
}

template<int DIR, int NS>
__device__ __forceinline__ void fft_stage(int j, const float2* src, float2* dst){
  float2 v[4];
#pragma unroll
  for(int r=0;r<4;r++) v[r]=src[SWZ(j+256*r)];
  bfly4<DIR>(v,j,NS);
  int base = ((j & ~(NS-1))<<2) | (j&(NS-1));
#pragma unroll
  for(int r=0;r<4;r++) dst[SWZ(base+NS*r)]=v[r];
}

template<int DIR>
__device__ __forceinline__ void fft1024_core(float2 v[4], int j, float2* A, float2* B, float scale){
  bfly4<DIR>(v,j,1);
#pragma unroll
  for(int r=0;r<4;r++) A[SWZ(4*j+r)]=v[r];
  __syncthreads();
  fft_stage<DIR,4 >(j,A,B); __syncthreads();
  fft_stage<DIR,16>(j,B,A); __syncthreads();
  fft_stage<DIR,64>(j,A,B); __syncthreads();
#pragma unroll
  for(int r=0;r<4;r++) v[r]=B[SWZ(j+256*r)];
  bfly4<DIR>(v,j,256);
#pragma unroll
  for(int r=0;r<4;r++){ v[r].x*=scale; v[r].y*=scale; }
}

template<int DIR>
__global__ __launch_bounds__(256) void k_fft_rows(const float2* src, float2* dst, float scale){
  __shared__ float2 A[1088], B[1088];
  int j = threadIdx.x;
  const float2* s = src + (size_t)blockIdx.x*W_;
  float2 v[4];
#pragma unroll
  for(int r=0;r<4;r++) v[r]=s[j+256*r];
  fft1024_core<DIR>(v,j,A,B,scale);
  float2* d = dst + (size_t)blockIdx.x*W_;
#pragma unroll
  for(int r=0;r<4;r++) d[j+256*r]=v[r];
}

// 1 column per block, registers-direct; XCD-aware column swizzle so the 8
// columns sharing each 64B line live on one XCD's L2.
template<int DIR>
__global__ __launch_bounds__(256) void k_fft_cols1(float2* data, float scale){
  __shared__ float2 A[1088], B[1088];
  int tid=threadIdx.x;
  int col = ((blockIdx.x&7)<<7) + (blockIdx.x>>3);
  float2 v[4];
#pragma unroll
  for(int r=0;r<4;r++) v[r]=data[(size_t)(tid+256*r)*W_ + col];
  fft1024_core<DIR>(v,tid,A,B,scale);
#pragma unroll
  for(int r=0;r<4;r++) data[(size_t)(tid+256*r)*W_ + col]=v[r];
}

// ---------------------------------------------------------------- init
__global__ __launch_bounds__(256) void k_pack(const float* xr, const float* xi, float2* X, float* t){
  int i = blockIdx.x*256+threadIdx.x;
  if (i<HW_) X[i]=make_float2(xr[i],xi[i]);
  if (blockIdx.x==0 && threadIdx.x<32) t[threadIdx.x]=0.f;
}

__global__ __launch_bounds__(256) void k_hist(const float* kt, int* counts, float* pmax){
  int m = blockIdx.x*256+threadIdx.x;
  float r = 0.f;
  {
    float kx=kt[2*m], ky=kt[2*m+1];
    float dx=kx-0.5f, dy=ky-0.5f;
    r = sqrtf(dx*dx+dy*dy);
    int ix = ((int)floorf(kx*1024.f))&1023;
    int iy = ((int)floorf(ky*1024.f))&1023;
    atomicAdd(&counts[(ix<<10)|iy],1);
  }
  for(int o=32;o>0;o>>=1) r = fmaxf(r, __shfl_down(r,o,64));
  __shared__ float sm[4];
  if((threadIdx.x&63)==0) sm[threadIdx.x>>6]=r;
  __syncthreads();
  if(threadIdx.x==0)
    pmax[blockIdx.x] = fmaxf(fmaxf(sm[0],sm[1]),fmaxf(sm[2],sm[3]));
}

__global__ __launch_bounds__(256) void k_reduce_max(const float* pmax, float* t){
  int tid=threadIdx.x;
  float s=-1e30f;
  for(int k=tid;k<2048;k+=256) s=fmaxf(s,pmax[k]);
  __shared__ float sm[4];
  for(int o=32;o>0;o>>=1) s=fmaxf(s,__shfl_down(s,o,64));
  if((tid&63)==0) sm[tid>>6]=s;
  __syncthreads();
  if(tid==0) t[15]=fmaxf(fmaxf(sm[0],sm[1]),fmaxf(sm[2],sm[3]));
}

// ---------------------------------------------------------------- scan
__global__ __launch_bounds__(256) void k_scan1(const int* cnt, int* off, int* bsum){
  __shared__ int sm[256];
  int base = blockIdx.x*1024;
  int tid = threadIdx.x;
  int4 c = *(const int4*)(cnt + base + tid*4);
  int s = c.x+c.y+c.z+c.w;
  sm[tid]=s; __syncthreads();
  int v=s;
  for(int o=1;o<256;o<<=1){
    int u = (tid>=o)? sm[tid-o]:0;
    __syncthreads();
    v += u; sm[tid]=v;
    __syncthreads();
  }
  int excl = v - s;
  int4 o4;
  o4.x=excl; o4.y=excl+c.x; o4.z=excl+c.x+c.y; o4.w=excl+c.x+c.y+c.z;
  *(int4*)(off+base+tid*4)=o4;
  if (tid==255) bsum[blockIdx.x]=v;
}

__global__ __launch_bounds__(256) void k_scan2(int* bsum){
  __shared__ int sm[256];
  int tid=threadIdx.x;
  int4 c = *(const int4*)(bsum + tid*4);
  int s = c.x+c.y+c.z+c.w;
  sm[tid]=s; __syncthreads();
  int v=s;
  for(int o=1;o<256;o<<=1){
    int u = (tid>=o)? sm[tid-o]:0;
    __syncthreads();
    v += u; sm[tid]=v;
    __syncthreads();
  }
  int excl=v-s;
  int4 o4;
  o4.x=excl; o4.y=excl+c.x; o4.z=excl+c.x+c.y; o4.w=excl+c.x+c.y+c.z;
  *(int4*)(bsum+tid*4)=o4;
}

__global__ __launch_bounds__(256) void k_scan3(int* off, const int* bbase){
  int gid = blockIdx.x*256+threadIdx.x;
  int b = bbase[gid>>8];
  int4 v = *(int4*)(off + gid*4);
  v.x+=b; v.y+=b; v.z+=b; v.w+=b;
  *(int4*)(off + gid*4)=v;
}

// ---------------------------------------------------------------- fused reorder: cell place + dcf + pd write in one pass
// pd[p] = (tx, ty, y_dcf.x, y_dcf.y)  (sorted-by-cell point data)
__global__ __launch_bounds__(256) void k_reorder12(const float* __restrict__ kt,
                                                   const float* __restrict__ kre,
                                                   const float* __restrict__ kim,
                                                   int* __restrict__ off,
                                                   float4* __restrict__ pd,
                                                   const float* __restrict__ t){
  int m = blockIdx.x*256+threadIdx.x;
  float kx=kt[2*m], ky=kt[2*m+1];
  float gx=kx*1024.f, gy=ky*1024.f;
  float fx=floorf(gx), fy=floorf(gy);
  float tx=gx-fx, ty=gy-fy;
  int ix=((int)fx)&1023, iy=((int)fy)&1023;
  int pos = atomicAdd(&off[(ix<<10)|iy],1);
  float dx=kx-0.5f, dy=ky-0.5f;
  float r=sqrtf(dx*dx+dy*dy);
  float dcf=sqrtf(r/(t[15]+1e-8f));
  pd[pos]=make_float4(tx,ty,kre[m]*dcf,kim[m]*dcf);
}

// ---------------------------------------------------------------- build T = Grid∘Sample as 5 symmetric stencil planes (fp32)
// + Gy = Grid(y*sqrt_dcf) in the same CSR walk.
// Wd[c] = T[c][c+d] = sum_p w_p(c)*w_p(c+d), d in {(0,0),(0,1),(1,0),(1,1),(1,-1)}
__global__ __launch_bounds__(256) void k_mkWG(const float4* __restrict__ pd,
                                              const int* __restrict__ off,
                                              float* __restrict__ Wp,
                                              float2* __restrict__ Gy){
  int gid=blockIdx.x*256+threadIdx.x;
  int r=gid>>8, c0=(gid&255)<<2;
  float w00[4],wE[4],wS[4],wSE[4],wSW[4],gx[4],gy[4];
#pragma unroll
  for(int q=0;q<4;q++){ w00[q]=0.f;wE[q]=0.f;wS[q]=0.f;wSE[q]=0.f;wSW[q]=0.f;gx[q]=0.f;gy[q]=0.f; }
#pragma unroll
  for(int dr=0;dr<2;dr++){
    int br=(r-dr)&1023;
    int rowbase=br<<10;
    if (c0>0){
      int O[6];
#pragma unroll
      for(int q=0;q<6;q++) O[q]=off[rowbase+c0-2+q];
#pragma unroll
      for(int i=0;i<5;i++){
        for(int j=O[i]; j<O[i+1]; j++){
          float4 p=pd[j];
          float wx = dr? p.x : 1.f-p.x;
          float uy=1.f-p.y, vy=p.y;
          float a0=wx*uy, a1=wx*vy;          // weights at cols pc, pc+1 (this cell row)
          float wpu=p.x*uy, wpv=p.x*vy;      // partner-row (r+1) weights (valid when dr==0)
          if (i>=1){                          // B=0 cell (col = pc) at slot i-1
            w00[i-1]=fmaf(a0,a0,w00[i-1]);
            wE [i-1]=fmaf(a0,a1,wE [i-1]);
            gx [i-1]=fmaf(a0,p.z,gx[i-1]); gy[i-1]=fmaf(a0,p.w,gy[i-1]);
            if(!dr){ wS[i-1]=fmaf(a0,wpu,wS[i-1]); wSE[i-1]=fmaf(a0,wpv,wSE[i-1]); }
          }
          if (i<=3){                          // B=1 cell (col = pc+1) at slot i
            w00[i]=fmaf(a1,a1,w00[i]);
            gx [i]=fmaf(a1,p.z,gx[i]); gy[i]=fmaf(a1,p.w,gy[i]);
            if(!dr){ wS[i]=fmaf(a1,wpv,wS[i]); wSW[i]=fmaf(a1,wpu,wSW[i]); }
          }
        }
      }
    } else {
      int bw=rowbase+1023;
      int sw=off[bw-1], ew=off[bw];
      for(int j=sw;j<ew;j++){                 // wrap: cell col 1023's points, B=1 at slot 0
        float4 p=pd[j];
        float wx = dr? p.x : 1.f-p.x;
        float uy=1.f-p.y, vy=p.y;
        float a1=wx*vy;
        w00[0]=fmaf(a1,a1,w00[0]);
        gx [0]=fmaf(a1,p.z,gx[0]); gy[0]=fmaf(a1,p.w,gy[0]);
        if(!dr){ float wpu=p.x*uy, wpv=p.x*vy;
          wS[0]=fmaf(a1,wpv,wS[0]); wSW[0]=fmaf(a1,wpu,wSW[0]); }
      }
      int O[5];
      O[0]=(rowbase==0)?0:off[rowbase-1];
#pragma unroll
      for(int q=1;q<5;q++) O[q]=off[rowbase+q-1];
#pragma unroll
      for(int i=0;i<4;i++){
        for(int j=O[i]; j<O[i+1]; j++){
          float4 p=pd[j];
          float wx = dr? p.x : 1.f-p.x;
          float uy=1.f-p.y, vy=p.y;
          float a0=wx*uy, a1=wx*vy;
          float wpu=p.x*uy, wpv=p.x*vy;
          w00[i]=fmaf(a0,a0,w00[i]);
          wE [i]=fmaf(a0,a1,wE [i]);
          gx [i]=fmaf(a0,p.z,gx[i]); gy[i]=fmaf(a0,p.w,gy[i]);
          if(!dr){ wS[i]=fmaf(a0,wpu,wS[i]); wSE[i]=fmaf(a0,wpv,wSE[i]); }
          if (i<=2){
            w00[i+1]=fmaf(a1,a1,w00[i+1]);
            gx [i+1]=fmaf(a1,p.z,gx[i+1]); gy[i+1]=fmaf(a1,p.w,gy[i+1]);
            if(!dr){ wS[i+1]=fmaf(a1,wpv,wS[i+1]); wSW[i+1]=fmaf(a1,wpu,wSW[i+1]); }
          }
        }
      }
    }
  }
  size_t base=((size_t)r<<10)+c0;
  *(float4*)&Wp[base]              = make_float4(w00[0],w00[1],w00[2],w00[3]);
  *(float4*)&Wp[(size_t)HW_+base]  = make_float4(wE[0],wE[1],wE[2],wE[3]);
  *(float4*)&Wp[(size_t)2*HW_+base]= make_float4(wS[0],wS[1],wS[2],wS[3]);
  *(float4*)&Wp[(size_t)3*HW_+base]= make_float4(wSE[0],wSE[1],wSE[2],wSE[3]);
  *(float4*)&Wp[(size_t)4*HW_+base]= make_float4(wSW[0],wSW[1],wSW[2],wSW[3]);
#pragma unroll
  for(int q=0;q<4;q++) Gy[base+q]=make_float2(gx[q],gy[q]);
}

// ---------------------------------------------------------------- 9-tap symmetric stencil, complex field (fp32 weights)
__device__ __forceinline__ float2 t_tap(const float2* __restrict__ Fm, const float2* __restrict__ F0,
                                        const float2* __restrict__ Fp, const float* __restrict__ Wp,
                                        int rowW, int rowWm, int c){
  int cm=(c+1023)&1023, cp=(c+1)&1023;
  const float* W00=Wp;
  const float* WE =Wp+(size_t)HW_;
  const float* WS =Wp+(size_t)2*HW_;
  const float* WSE=Wp+(size_t)3*HW_;
  const float* WSW=Wp+(size_t)4*HW_;
  float2 f=F0[c];
  float w=W00[rowW+c];
  float ux=w*f.x, uy=w*f.y;
  f=F0[cp]; w=WE [rowW +c ]; ux=fmaf(w,f.x,ux); uy=fmaf(w,f.y,uy);  // +E
  f=F0[cm]; w=WE [rowW +cm]; ux=fmaf(w,f.x,ux); uy=fmaf(w,f.y,uy);  // -E
  f=Fp[c ]; w=WS [rowW +c ]; ux=fmaf(w,f.x,ux); uy=fmaf(w,f.y,uy);  // +S
  f=Fm[c ]; w=WS [rowWm+c ]; ux=fmaf(w,f.x,ux); uy=fmaf(w,f.y,uy);  // -S
  f=Fp[cp]; w=WSE[rowW +c ]; ux=fmaf(w,f.x,ux); uy=fmaf(w,f.y,uy);  // +SE
  f=Fm[cm]; w=WSE[rowWm+cm]; ux=fmaf(w,f.x,ux); uy=fmaf(w,f.y,uy);  // -SE
  f=Fp[cm]; w=WSW[rowW +c ]; ux=fmaf(w,f.x,ux); uy=fmaf(w,f.y,uy);  // +SW
  f=Fm[cp]; w=WSW[rowWm+cp]; ux=fmaf(w,f.x,ux); uy=fmaf(w,f.y,uy);  // -SW
  return make_float2(ux,uy);
}

// ---------------------------------------------------------------- 9-tap stencil, REAL field (power iteration)
__device__ __forceinline__ float t_tap_r(const float* __restrict__ Fm, const float* __restrict__ F0,
                                         const float* __restrict__ Fp, const float* __restrict__ Wp,
                                         int rowW, int rowWm, int c){
  int cm=(c+1023)&1023, cp=(c+1)&1023;
  const float* W00=Wp;
  const float* WE =Wp+(size_t)HW_;
  const float* WS =Wp+(size_t)2*HW_;
  const float* WSE=Wp+(size_t)3*HW_;
  const float* WSW=Wp+(size_t)4*HW_;
  float u = W00[rowW+c]*F0[c];
  u=fmaf(WE [rowW +c ],F0[cp],u);
  u=fmaf(WE [rowW +cm],F0[cm],u);
  u=fmaf(WS [rowW +c ],Fp[c ],u);
  u=fmaf(WS [rowWm+c ],Fm[c ],u);
  u=fmaf(WSE[rowW +c ],Fp[cp],u);
  u=fmaf(WSE[rowWm+cm],Fm[cm],u);
  u=fmaf(WSW[rowW +c ],Fp[cm],u);
  u=fmaf(WSW[rowWm+cp],Fm[cp],u);
  return u;
}

// ---------------------------------------------------------------- power phase (REAL): S_1 = 1024 * T(:,DC)
// (V0 = FFT(ones) = 1024*delta; all iterates are exactly real since T is real.)
__global__ __launch_bounds__(256) void k_TinitR(float* __restrict__ S, const float* __restrict__ Wp, float* pb){
  int r=blockIdx.x, tid=threadIdx.x;
  float nsq=0.f;
  float* row = S + ((size_t)r<<10);
#pragma unroll
  for(int q=0;q<4;q++){
    int c=tid+256*q;
    float val=0.f;
    if (r==0){
      if (c==0) val=Wp[0];
      else if (c==1) val=Wp[(size_t)HW_];
      else if (c==1023) val=Wp[(size_t)HW_+1023];
    } else if (r==1){
      if (c==0) val=Wp[(size_t)2*HW_];
      else if (c==1) val=Wp[(size_t)3*HW_];
      else if (c==1023) val=Wp[(size_t)4*HW_];
    } else if (r==1023){
      if (c==0) val=Wp[(size_t)2*HW_+(1023<<10)];
      else if (c==1) val=Wp[(size_t)4*HW_+(1023<<10)+1];
      else if (c==1023) val=Wp[(size_t)3*HW_+(1023<<10)+1023];
    }
    val *= 1024.f;
    row[c]=val;
    nsq=fmaf(val,val,nsq);
  }
  __shared__ float sm4[4];
  for(int o=32;o>0;o>>=1) nsq+=__shfl_down(nsq,o,64);
  if((tid&63)==0) sm4[tid>>6]=nsq;
  __syncthreads();
  if(tid==0) pb[r]=sm4[0]+sm4[1]+sm4[2]+sm4[3];
}

// real power step: S_out = sc*T(S_in), sc=1/(||S_in||+1e-12)
// pa[r] = row dot(S_in, T S_in); pbOut[r] = row ||S_out||^2; if last: t[0]=sc, t[1]=||S_in||^2
__global__ __launch_bounds__(256) void k_TpowR(const float* __restrict__ Sin, float* __restrict__ Sout,
    const float* __restrict__ Wp, const float* __restrict__ pbIn,
    float* pbOut, float* pa, float* t, int last){
  __shared__ __align__(16) float Fsm[3][1024];
  __shared__ float smr[8];
  int r=blockIdx.x, tid=threadIdx.x;
  // reduce pbIn -> b (redundant per block; 4KB L2-resident)
  float s=0.f;
  for(int k=tid;k<1024;k+=256) s+=pbIn[k];
  for(int o=32;o>0;o>>=1) s+=__shfl_down(s,o,64);
  if((tid&63)==0) smr[tid>>6]=s;
  // stage 3 rows of S_in (256 float4 per row -> one per thread)
  int rm=(r+1023)&1023, rp=(r+1)&1023;
  ((float4*)Fsm[0])[tid] = ((const float4*)(Sin+((size_t)rm<<10)))[tid];
  ((float4*)Fsm[1])[tid] = ((const float4*)(Sin+((size_t)r <<10)))[tid];
  ((float4*)Fsm[2])[tid] = ((const float4*)(Sin+((size_t)rp<<10)))[tid];
  __syncthreads();
  float b=smr[0]+smr[1]+smr[2]+smr[3];
  float sc=1.f/(sqrtf(b)+1e-12f);
  if (last && r==0 && tid==0){ t[0]=sc; t[1]=b; }
  int rowW=r<<10, rowWm=rm<<10;
  float dotp=0.f, nsq=0.f;
  float outv[4];
#pragma unroll
  for(int q=0;q<4;q++){
    int c=tid+256*q;
    float u=t_tap_r(Fsm[0],Fsm[1],Fsm[2],Wp,rowW,rowWm,c);
    dotp=fmaf(Fsm[1][c],u,dotp);
    float ox=u*sc;
    nsq=fmaf(ox,ox,nsq);
    outv[q]=ox;
  }
  float* orow=Sout+((size_t)r<<10);
#pragma unroll
  for(int q=0;q<4;q++) orow[tid+256*q]=outv[q];
  for(int o=32;o>0;o>>=1){ dotp+=__shfl_down(dotp,o,64); nsq+=__shfl_down(nsq,o,64); }
  __syncthreads();
  if((tid&63)==0){ smr[tid>>6]=dotp; smr[4+(tid>>6)]=nsq; }
  __syncthreads();
  if(tid==0){ pa[r]=smr[0]+smr[1]+smr[2]+smr[3]; pbOut[r]=smr[4]+smr[5]+smr[6]+smr[7]; }
}

// op_norm = ||av_10|| / (||v_9||+1e-12); t[19] = 2*sigmoid(w_raw)/op_norm^2
__global__ __launch_bounds__(256) void k_Tfinal(const float* __restrict__ pa,
                                                const float* __restrict__ wraw, float* t){
  int tid=threadIdx.x;
  float s=0.f;
  for(int k=tid;k<1024;k+=256) s+=pa[k];
  __shared__ float sm4[4];
  for(int o=32;o>0;o>>=1) s+=__shfl_down(s,o,64);
  if((tid&63)==0) sm4[tid>>6]=s;
  __syncthreads();
  if(tid==0){
    float raw=sm4[0]+sm4[1]+sm4[2]+sm4[3];
    float sc=t[0], b=t[1];
    float a=sc*sc*raw;            // ||av_10||^2
    float vn=sqrtf(b)*sc;         // ||v_9||
    float opn=sqrtf(a)/(vn+1e-12f);
    float sig=1.f/(1.f+__expf(-wraw[0]));
    t[19]=2.f*sig/(opn*opn);
  }
}

// ---------------------------------------------------------------- npcg: G2_row = rowIFFT( T*F - Gy ), block = k-grid row
__global__ __launch_bounds__(256) void k_Tsub_fft(const float2* __restrict__ Fin,
    const float* __restrict__ Wp, const float2* __restrict__ Gy,
    float2* __restrict__ G2, float scale){
  __shared__ __align__(16) float2 Fsm[3][1024];   // reused as FFT scratch A|B after taps
  int r=blockIdx.x, tid=threadIdx.x;
  int rm=(r+1023)&1023, rp=(r+1)&1023;
  {
    const float4* s0=(const float4*)(Fin+((size_t)rm<<10));
    const float4* s1=(const float4*)(Fin+((size_t)r <<10));
    const float4* s2=(const float4*)(Fin+((size_t)rp<<10));
    float4* f0=(float4*)Fsm[0]; float4* f1=(float4*)Fsm[1]; float4* f2=(float4*)Fsm[2];
    for(int p2=tid;p2<512;p2+=256){ f0[p2]=s0[p2]; f1[p2]=s1[p2]; f2[p2]=s2[p2]; }
  }
  __syncthreads();
  int rowW=r<<10, rowWm=rm<<10;
  float2 v[4];
  const float2* gyr=Gy+((size_t)r<<10);
#pragma unroll
  for(int q=0;q<4;q++){
    int c=tid+256*q;
    float2 u=t_tap(&Fsm[0][0],&Fsm[1][0],&Fsm[2][0],Wp,rowW,rowWm,c);
    float2 gy=gyr[c];
    v[q]=make_float2(u.x-gy.x,u.y-gy.y);   // note: c = tid+256q IS the fft1024_core input layout
  }
  __syncthreads();                          // all Fsm reads done before aliasing
  float2* A=(float2*)Fsm; float2* B=A+1088;
  fft1024_core<1>(v,tid,A,B,scale);
  float2* d=G2+((size_t)r<<10);
#pragma unroll
  for(int rr=0;rr<4;rr++) d[tid+256*rr]=v[rr];
}

// ---------------------------------------------------------------- composed-conv tables
// ec layout (floats): [0..99] E[oc*50+ic*25+dy*5+dx]; [100..101] C0;
// [102..119] Bb[oc*9+u]; [120..443] Btab[oc*162+u*18+ic*9+v]; [444..445] b2
__global__ __launch_bounds__(256) void k_mkE(const float* w1, const float* b1,
                                             const float* w2, const float* b2, float* ec){
  __shared__ float sw1[576], sw2[576], sb1[32], sB[324];
  int tid=threadIdx.x;
  for(int p=tid;p<576;p+=256){ sw1[p]=w1[p]; sw2[p]=w2[p]; }
  if(tid<32) sb1[tid]=b1[tid];
  __syncthreads();
  for(int e=tid;e<324;e+=256){
    int oc=e/162, r=e-oc*162, u=r/18, r2=r-u*18, ic=r2/9, v=r2-ic*9;
    float s=0.f;
    for(int cm=0;cm<32;cm++) s=fmaf(sw2[oc*288+cm*9+u], sw1[cm*18+ic*9+v], s);
    sB[e]=s; ec[120+e]=s;
  }
  if(tid<18){
    int oc=tid/9, u=tid-oc*9;
    float s=0.f;
    for(int cm=0;cm<32;cm++) s=fmaf(sw2[oc*288+cm*9+u], sb1[cm], s);
    ec[102+tid]=s;
  }
  if(tid<2){
    float s=b2[tid];
    for(int u=0;u<9;u++){
      float bb=0.f;
      for(int cm=0;cm<32;cm++) bb=fmaf(sw2[tid*288+cm*9+u], sb1[cm], bb);
      s+=bb;
    }
    ec[100+tid]=s;
    ec[444+tid]=b2[tid];
  }
  __syncthreads();
  if(tid<100){
    int oc=tid/50, r=tid-oc*50, ic=r/25, r2=r-ic*25, dy=r2/5, dx=r2-dy*5;
    float s=0.f;
    for(int uy=0;uy<3;uy++){ int vy=dy-uy; if(vy<0||vy>2) continue;
      for(int ux=0;ux<3;ux++){ int vx=dx-ux; if(vx<0||vx>2) continue;
        s+=sB[oc*162+(uy*3+ux)*18+ic*9+vy*3+vx];
      }
    }
    ec[tid]=s;
  }
}

// ---------------------------------------------------------------- fused 5x5 composed CNN + update
// blocks 0..1023: interior tiles (skip border pixels); blocks 1024..1039: border ring
#define CT_S 41
__global__ __launch_bounds__(256) void k_cnn5(const float2* __restrict__ x, const float2* __restrict__ res,
    const float* __restrict__ ec, const float* __restrict__ t,
    float2* __restrict__ xout, float* __restrict__ outPlanar){
  int tid=threadIdx.x;
  if (blockIdx.x>=1024){
    // ---- border ring: exact conv2(conv1) with h zero-masked outside image
    int id = (blockIdx.x-1024)*256+tid;   // 4096
    int py,px;
    if (id<1024){ py=0; px=id; }
    else if(id<2048){ py=1023; px=id-1024; }
    else if(id<3072){ py=id-2048; px=0; }
    else { py=id-3072; px=1023; }
    float s0=ec[444], s1=ec[445];
    for(int uy=0;uy<3;uy++){
      int qy=py+uy-1; if((unsigned)qy>=1024u) continue;
      for(int ux=0;ux<3;ux++){
        int qx=px+ux-1; if((unsigned)qx>=1024u) continue;
        int u=uy*3+ux;
        s0+=ec[102+u]; s1+=ec[111+u];
        const float* B0=&ec[120+u*18];
        const float* B1=&ec[282+u*18];
        for(int vy=0;vy<3;vy++){
          int sy2=qy+vy-1; if((unsigned)sy2>=1024u) continue;
          for(int vx=0;vx<3;vx++){
            int sx2=qx+vx-1; if((unsigned)sx2>=1024u) continue;
            int v=vy*3+vx;
            float2 xv=x[(size_t)sy2*W_+sx2];
            s0 = fmaf(B0[v],xv.x,fmaf(B0[9+v],xv.y,s0));
            s1 = fmaf(B1[v],xv.x,fmaf(B1[9+v],xv.y,s1));
          }
        }
      }
    }
    float wreg=t[19];
    size_t base=(size_t)py*W_+px;
    float2 xv=x[base], rv=res[base];
    float o0=xv.x - wreg*rv.x - s0;
    float o1=xv.y - wreg*rv.y - s1;
    if (outPlanar){ outPlanar[base]=o0; outPlanar[HW_+base]=o1; }
    else          { xout[base]=make_float2(o0,o1); }
    return;
  }
  __shared__ float xt0[36*CT_S];
  __shared__ float xt1[36*CT_S];
  __shared__ float sE[102];
  int by=blockIdx.x>>5, bx=blockIdx.x&31;
  int ty0=by<<5, tx0=bx<<5;
  for(int p=tid;p<102;p+=256) sE[p]=ec[p];
  for(int p=tid;p<1296;p+=256){
    int r=p/36, c=p-r*36;
    int gy=ty0-2+r, gx=tx0-2+c;
    float vx=0.f, vy=0.f;
    if((unsigned)gy<1024u && (unsigned)gx<1024u){ float2 v=x[(size_t)gy*W_+gx]; vx=v.x; vy=v.y; }
    xt0[r*CT_S+c]=vx; xt1[r*CT_S+c]=vy;
  }
  __syncthreads();
  int row=tid>>3, c4=(tid&7)<<2;
  float a0[4], a1[4];
  float C00=sE[100], C01=sE[101];
#pragma unroll
  for(int jj=0;jj<4;jj++){ a0[jj]=C00; a1[jj]=C01; }
#pragma unroll
  for(int dy=0;dy<5;dy++){
    const float* r0=&xt0[(row+dy)*CT_S+c4];
    const float* r1=&xt1[(row+dy)*CT_S+c4];
    float f0[9], f1[9];
#pragma unroll
    for(int q=0;q<9;q++){ f0[q]=r0[q]; f1[q]=r1[q]; }
#pragma unroll
    for(int dx=0;dx<5;dx++){
      float e00=sE[dy*5+dx], e01=sE[25+dy*5+dx];
      float e10=sE[50+dy*5+dx], e11=sE[75+dy*5+dx];
#pragma unroll
      for(int jj=0;jj<4;jj++){
        a0[jj]=fmaf(e00,f0[jj+dx],fmaf(e01,f1[jj+dx],a0[jj]));
        a1[jj]=fmaf(e10,f0[jj+dx],fmaf(e11,f1[jj+dx],a1[jj]));
      }
    }
  }
  int py=ty0+row;
  float wreg = t[19];
  size_t base=(size_t)py*W_ + tx0 + c4;
  bool rowEdge = (py==0)||(py==1023);
  if (outPlanar){
#pragma unroll
    for(int jj=0;jj<4;jj++){
      int px=tx0+c4+jj;
      if (rowEdge || px==0 || px==1023) continue;   // ring blocks own these
      float2 rv=res[base+jj];
      float xr_=xt0[(row+2)*CT_S+c4+jj+2];
      float xi_=xt1[(row+2)*CT_S+c4+jj+2];
      outPlanar[base+jj]      = xr_ - wreg*rv.x - a0[jj];
      outPlanar[HW_+base+jj]  = xi_ - wreg*rv.y - a1[jj];
    }
  } else {
#pragma unroll
    for(int jj=0;jj<4;jj++){
      int px=tx0+c4+jj;
      if (rowEdge || px==0 || px==1023) continue;
      float2 rv=res[base+jj];
      float xr_=xt0[(row+2)*CT_S+c4+jj+2];
      float xi_=xt1[(row+2)*CT_S+c4+jj+2];
      xout[base+jj]=make_float2(xr_ - wreg*rv.x - a0[jj],
                                xi_ - wreg*rv.y - a1[jj]);
    }
  }
}

// ================================================================ launch
extern "C" void kernel_launch(void* const* d_in, const int* in_sizes, int n_in,
                              void* d_out, int out_size, void* d_ws, size_t ws_size,
                              hipStream_t stream){
  (void)in_sizes; (void)n_in; (void)out_size; (void)ws_size;
  const float* xr  =(const float*)d_in[0];
  const float* xi  =(const float*)d_in[1];
  const float* kre =(const float*)d_in[2];
  const float* kim =(const float*)d_in[3];
  const float* kt  =(const float*)d_in[4];
  const float* wraw=(const float*)d_in[5];
  const float* w1  =(const float*)d_in[6];
  const float* b1  =(const float*)d_in[7];
  const float* w2  =(const float*)d_in[8];
  const float* b2  =(const float*)d_in[9];
  float* out = (float*)d_out;

  char* ws=(char*)d_ws;
  float2* Wx0 =(float2*)(ws);                      // 8MB
  float2* Wx1 =(float2*)(ws + ((size_t) 8<<20));   // 8MB
  int*   counts=(int*)  (ws + ((size_t) 8<<20));   // 4MB alias of Wx1 (setup only)
  float2* WF  =(float2*)(ws + ((size_t)16<<20));   // 8MB  fwd-FFT grid (npcg); power S0/S1 (real) alias inside
  float4* pd  =(float4*)(ws + ((size_t)24<<20));   // 8MB  (tx,ty,ydcf.x,ydcf.y) sorted
  float2* G2  =(float2*)(ws + ((size_t)32<<20));   // 8MB  npcg residual grid
  int*  off   =(int*)   (ws + ((size_t)40<<20));   // 4MB  CSR ends
  float2* Gy  =(float2*)(ws + ((size_t)44<<20));   // 8MB  Grid(y*sqrt_dcf)
  float* Wp   =(float*) (ws + ((size_t)52<<20));   // 20MB 5 stencil planes (fp32)
  float* S0R  =(float*)WF;                         // 4MB  power ping (real), alias WF[0:4MB)
  float* S1R  =((float*)WF)+HW_;                   // 4MB  power pong (real), alias WF[4:8MB)
  int*  bsum  =(int*)   (ws + ((size_t)72<<20));            // 4KB
  float* t    =(float*) (ws + ((size_t)72<<20) + 8192);
  float* ec   =(float*) (ws + ((size_t)72<<20) + 16384);
  float* pa   =(float*) (ws + ((size_t)72<<20) + 32768);    // 4KB
  float* pb0  =(float*) (ws + ((size_t)72<<20) + 40960);    // 4KB
  float* pb1  =(float*) (ws + ((size_t)72<<20) + 49152);    // 4KB
  float* pmax =(float*) (ws + ((size_t)72<<20) + 57344);    // 8KB
  const float SC = 0.03125f;   // 1/32 per 1-D ortho pass

  // ---- setup
  k_pack<<<HW_/256,256,0,stream>>>(xr,xi,Wx0,t);
  k_mkE<<<1,256,0,stream>>>(w1,b1,w2,b2,ec);
  hipMemsetAsync(counts,0,(size_t)HW_*sizeof(int),stream);
  k_hist<<<M_/256,256,0,stream>>>(kt,counts,pmax);
  k_reduce_max<<<1,256,0,stream>>>(pmax,t);
  k_scan1<<<1024,256,0,stream>>>(counts,off,bsum);
  k_scan2<<<1,256,0,stream>>>(bsum);
  k_scan3<<<1024,256,0,stream>>>(off,bsum);
  k_reorder12<<<M_/256,256,0,stream>>>(kt,kre,kim,off,pd,t);
  k_mkWG<<<HW_/1024,256,0,stream>>>(pd,off,Wp,Gy);

  // ---- power iteration (REAL field): init + 9 single steps + final
  k_TinitR<<<H_,256,0,stream>>>(S0R,Wp,pb0);
  for (int n=0;n<9;n++){
    float* si=(n&1)?S1R:S0R; float* so=(n&1)?S0R:S1R;
    float* pi=(n&1)?pb1:pb0; float* po=(n&1)?pb0:pb1;
    k_TpowR<<<H_,256,0,stream>>>(si,so,Wp,pi,po,pa,t,(n==8)?1:0);
  }
  k_Tfinal<<<1,256,0,stream>>>(pa,wraw,t);

  // ---- npcg = 4 PGD iterations
  for (int it=0; it<4; it++){
    float2* xin  = (it&1)? Wx1 : Wx0;
    float2* xout = (it&1)? Wx0 : Wx1;
    float* planar = (it==3)? out : (float*)nullptr;
    k_fft_rows<-1><<<H_,256,0,stream>>>(xin,WF,SC);
    k_fft_cols1<-1><<<H_,256,0,stream>>>(WF,SC);
    k_Tsub_fft<<<H_,256,0,stream>>>(WF,Wp,Gy,G2,SC);
    k_fft_cols1<1><<<H_,256,0,stream>>>(G2,SC);
    k_cnn5<<<1040,256,0,stream>>>(xin,G2,ec,t,xout,planar);
  }
}